// Round 11
// baseline (304.470 us; speedup 1.0000x reference)
//
#include <hip/hip_runtime.h>

#define HCC 128
#define NEG_SLOPE 0.2f
#define CHUNK 16

using bf16x8 = __attribute__((ext_vector_type(8))) __bf16;
using f32x4  = __attribute__((ext_vector_type(4))) float;

__device__ inline unsigned short f32_to_bf16(float v) {
  unsigned u = __float_as_uint(v);
  unsigned r = u + 0x7FFFu + ((u >> 16) & 1u);
  return (unsigned short)(r >> 16);
}
__device__ inline float bf16_to_f32(unsigned short h) {
  return __uint_as_float(((unsigned)h) << 16);
}

// fold-reduce step: k simultaneous 32-lane reductions, halving per step.
#define FOLD_STEP(S, CNT)                                    \
  {                                                          \
    _Pragma("unroll")                                        \
    for (int q = 0; q < CNT; q++) {                          \
      bool hi = (lane & S) != 0;                             \
      float give = hi ? pr[q] : pr[q + CNT];                 \
      float keep = hi ? pr[q + CNT] : pr[q];                 \
      pr[q] = keep + __shfl_xor(give, S);                    \
    }                                                        \
  }

// ---------------- init: zero deg, cursor, ea_sum (replaces 3 memsets) ----------------
__global__ void init_kernel(int* __restrict__ deg, int* __restrict__ cursor,
                            float* __restrict__ ea_sum, int N) {
  int i = blockIdx.x * blockDim.x + threadIdx.x;
  if (i < N) { deg[i] = 0; cursor[i] = 0; }
  if (i == N) ea_sum[0] = 0.f;
}

// ---------------- fused: degree count + edge_attr sum ----------------
__global__ void eadeg_kernel(const int* __restrict__ ei, const float* __restrict__ ea,
                             int* __restrict__ deg, float* __restrict__ ea_sum, int E, int N) {
  int k = blockIdx.x * blockDim.x + threadIdx.x;
  float acc = 0.f;
  if (k < E + N) {
    int t = (k < E) ? ei[E + k] : (k - E);
    atomicAdd(&deg[t], 1);
    if (k < E) acc = ea[k];
  }
  #pragma unroll
  for (int off = 32; off > 0; off >>= 1) acc += __shfl_down(acc, off);
  if ((threadIdx.x & 63) == 0) atomicAdd(ea_sum, acc);
}

// ---------------- per-1024-block sums ----------------
__global__ __launch_bounds__(1024) void blocksum_kernel(const int* __restrict__ deg,
                                                        int* __restrict__ bsum, int n) {
  __shared__ int ws[16];
  int i = blockIdx.x * 1024 + threadIdx.x;
  int v = (i < n) ? deg[i] : 0;
  int lane = threadIdx.x & 63, wid = threadIdx.x >> 6;
  #pragma unroll
  for (int off = 32; off > 0; off >>= 1) v += __shfl_xor(v, off);
  if (lane == 0) ws[wid] = v;
  __syncthreads();
  if (threadIdx.x < 16) {
    int t = ws[threadIdx.x];
    #pragma unroll
    for (int off = 8; off > 0; off >>= 1) t += __shfl_xor(t, off);
    if (threadIdx.x == 0) bsum[blockIdx.x] = t;
  }
}

// ---------------- final scan: every block wave-scans bsum (<=64) itself ----------------
__global__ __launch_bounds__(1024) void scanfinal_kernel(const int* __restrict__ deg,
    const int* __restrict__ bsum, int* __restrict__ offs, int n, int nb) {
  __shared__ int wsum[16];
  __shared__ int bbase, btot;
  int tid = threadIdx.x;
  if (tid < 64) {
    int v = (tid < nb) ? bsum[tid] : 0;
    int x = v;
    #pragma unroll
    for (int off = 1; off < 64; off <<= 1) {
      int y = __shfl_up(x, off);
      if (tid >= off) x += y;
    }
    if (tid == (int)blockIdx.x) bbase = x - v;  // exclusive base of this block
    if (tid == 63) btot = x;
  }
  __syncthreads();
  int i = blockIdx.x * 1024 + tid;
  int v = (i < n) ? deg[i] : 0;
  int lane = tid & 63, wid = tid >> 6;
  int x = v;
  #pragma unroll
  for (int off = 1; off < 64; off <<= 1) {
    int y = __shfl_up(x, off);
    if (lane >= off) x += y;
  }
  if (lane == 63) wsum[wid] = x;
  __syncthreads();
  if (tid < 16) {
    int t = wsum[tid];
    int s = t;
    #pragma unroll
    for (int off = 1; off < 16; off <<= 1) {
      int y = __shfl_up(s, off);
      if (tid >= off) s += y;
    }
    wsum[tid] = s - t;   // exclusive
  }
  __syncthreads();
  if (i < n) offs[i] = bbase + wsum[wid] + x - v;
  if (blockIdx.x == 0 && tid == 0) offs[n] = btot;
}

// ---------------- scatter edges into CSR-by-target (packed src+ea) ----------------
__global__ void scatter_kernel(const int* __restrict__ ei, const float* __restrict__ ea,
                               const float* __restrict__ ea_sum, const int* __restrict__ offs,
                               int* __restrict__ cursor, int2* __restrict__ csr_pack,
                               int E, int N) {
  int k = blockIdx.x * blockDim.x + threadIdx.x;
  if (k >= E + N) return;
  int s, t; float v;
  if (k < E) { s = ei[k]; t = ei[E + k]; v = ea[k]; }
  else       { s = t = k - E; v = ea_sum[0] * (1.0f / (float)E); }
  int pos = offs[t] + atomicAdd(&cursor[t], 1);
  csr_pack[pos] = make_int2(s, __float_as_int(v));
}

// ---------------- GATv2 layer 1, specialized for x of shape (N,1) ----------------
__global__ void gat1_kernel(const float* __restrict__ x,
    const int* __restrict__ offs, const int2* __restrict__ csr_pack,
    const float* __restrict__ Wl, const float* __restrict__ bl,
    const float* __restrict__ Wr, const float* __restrict__ br,
    const float* __restrict__ We, const float* __restrict__ att,
    const float* __restrict__ bias,
    unsigned short* __restrict__ h_hi, unsigned short* __restrict__ h_lo, int N) {
  int t = (blockIdx.x * blockDim.x + threadIdx.x) >> 6;
  if (t >= N) return;
  int lane = threadIdx.x & 63;
  int c = lane * 2;
  float2 wl = *(const float2*)&Wl[c];
  float2 wr = *(const float2*)&Wr[c];
  float2 we = *(const float2*)&We[c];
  float2 at = *(const float2*)&att[c];
  float2 bl2 = *(const float2*)&bl[c];
  float2 br2 = *(const float2*)&br[c];
  float xt = x[t];
  float base0 = fmaf(xt, wr.x, br2.x + bl2.x);
  float base1 = fmaf(xt, wr.y, br2.y + bl2.y);
  int e0 = offs[t], e1 = offs[t + 1];
  int qlane = (lane >> 1) & 15;
  int bb = lane & 32;

  float den = 0.f, S1 = 0.f;
  for (int base = e0; base < e1; base += CHUNK) {
    int eidx = base + (lane & 15);
    eidx = eidx < e1 ? eidx : e1 - 1;
    int2 pk = csr_pack[eidx];
    float xs[CHUNK], eav[CHUNK];
    #pragma unroll
    for (int q = 0; q < CHUNK; q++) {
      int s = __builtin_amdgcn_readlane(pk.x, q);
      eav[q] = __uint_as_float(__builtin_amdgcn_readlane(pk.y, q));
      xs[q] = x[s];
    }
    float pr[CHUNK];
    #pragma unroll
    for (int q = 0; q < CHUNK; q++) {
      float m0 = fmaf(xs[q], wl.x, fmaf(eav[q], we.x, base0));
      float m1 = fmaf(xs[q], wl.y, fmaf(eav[q], we.y, base1));
      float l0 = fmaxf(m0, NEG_SLOPE * m0);
      float l1 = fmaxf(m1, NEG_SLOPE * m1);
      pr[q] = fmaf(l0, at.x, l1 * at.y);
    }
    FOLD_STEP(16, 8) FOLD_STEP(8, 4) FOLD_STEP(4, 2) FOLD_STEP(2, 1)
    pr[0] += __shfl_xor(pr[0], 1);
    float wgt = (base + qlane < e1) ? __expf(pr[0]) : 0.f;
    // den via HALF-wave reduction (off<32 never crosses the head boundary):
    // within a 32-lane half each edge's wgt lives in exactly 2 lanes.
    float ws = wgt;
    #pragma unroll
    for (int off = 1; off < 32; off <<= 1) ws += __shfl_xor(ws, off);
    den = fmaf(ws, 0.5f, den);
    #pragma unroll
    for (int q = 0; q < CHUNK; q++) {
      float wq = __shfl(wgt, bb + 2 * q);
      S1 = fmaf(wq, xs[q], S1);
    }
  }
  float T = S1 / den;
  float2 bv = *(const float2*)&bias[c];
  float o0 = fmaxf(fmaf(wl.x, T, bl2.x + bv.x), 0.f);
  float o1 = fmaxf(fmaf(wl.y, T, bl2.y + bv.y), 0.f);
  unsigned short hh0 = f32_to_bf16(o0);
  unsigned short hl0 = f32_to_bf16(o0 - bf16_to_f32(hh0));
  unsigned short hh1 = f32_to_bf16(o1);
  unsigned short hl1 = f32_to_bf16(o1 - bf16_to_f32(hh1));
  *(ushort2*)&h_hi[(size_t)t * HCC + c] = make_ushort2(hh0, hh1);
  *(ushort2*)&h_lo[(size_t)t * HCC + c] = make_ushort2(hl0, hl1);
}

// ---------------- GATv2 layer 2: one wave per node ----------------
__global__ void gat2_kernel(const float* __restrict__ xl, const float* __restrict__ xr,
    const int* __restrict__ offs, const int2* __restrict__ csr_pack,
    const float* __restrict__ We, const float* __restrict__ att,
    const float* __restrict__ bias,
    unsigned short* __restrict__ h_hi, unsigned short* __restrict__ h_lo, int N) {
  int t = (blockIdx.x * blockDim.x + threadIdx.x) >> 6;
  if (t >= N) return;
  int lane = threadIdx.x & 63;
  int c = lane * 2;
  float2 xrv = *(const float2*)&xr[(size_t)t * HCC + c];
  float2 wev = *(const float2*)&We[c];
  float2 atv = *(const float2*)&att[c];
  int e0 = offs[t], e1 = offs[t + 1];
  int qlane = (lane >> 1) & 15;
  int bb = lane & 32;

  float den = 0.f, a0 = 0.f, a1 = 0.f;
  for (int base = e0; base < e1; base += CHUNK) {
    int eidx = base + (lane & 15);
    eidx = eidx < e1 ? eidx : e1 - 1;
    int2 pk = csr_pack[eidx];                 // 1 VMEM for all 16 edges
    float2 xj[CHUNK];
    #pragma unroll
    for (int q = 0; q < CHUNK; q++) {
      int s = __builtin_amdgcn_readlane(pk.x, q);
      xj[q] = *(const float2*)&xl[(size_t)s * HCC + c];
    }
    float pr[CHUNK];
    #pragma unroll
    for (int q = 0; q < CHUNK; q++) {
      float eav = __uint_as_float(__builtin_amdgcn_readlane(pk.y, q));
      float m0 = fmaf(eav, wev.x, xrv.x + xj[q].x);
      float m1 = fmaf(eav, wev.y, xrv.y + xj[q].y);
      float l0 = fmaxf(m0, NEG_SLOPE * m0);
      float l1 = fmaxf(m1, NEG_SLOPE * m1);
      pr[q] = fmaf(l0, atv.x, l1 * atv.y);
    }
    FOLD_STEP(16, 8) FOLD_STEP(8, 4) FOLD_STEP(4, 2) FOLD_STEP(2, 1)
    pr[0] += __shfl_xor(pr[0], 1);
    float wgt = (base + qlane < e1) ? __expf(pr[0]) : 0.f;
    // HALF-wave reduction: head-local denominator (2 lanes per edge per half)
    float ws = wgt;
    #pragma unroll
    for (int off = 1; off < 32; off <<= 1) ws += __shfl_xor(ws, off);
    den = fmaf(ws, 0.5f, den);
    #pragma unroll
    for (int q = 0; q < CHUNK; q++) {
      float wq = __shfl(wgt, bb + 2 * q);
      a0 = fmaf(wq, xj[q].x, a0);
      a1 = fmaf(wq, xj[q].y, a1);
    }
  }
  float inv = 1.0f / den;
  float2 bv = *(const float2*)&bias[c];
  float o0 = fmaxf(fmaf(a0, inv, bv.x), 0.f);
  float o1 = fmaxf(fmaf(a1, inv, bv.y), 0.f);
  unsigned short hh0 = f32_to_bf16(o0);
  unsigned short hl0 = f32_to_bf16(o0 - bf16_to_f32(hh0));
  unsigned short hh1 = f32_to_bf16(o1);
  unsigned short hl1 = f32_to_bf16(o1 - bf16_to_f32(hh1));
  *(ushort2*)&h_hi[(size_t)t * HCC + c] = make_ushort2(hh0, hh1);
  *(ushort2*)&h_lo[(size_t)t * HCC + c] = make_ushort2(hl0, hl1);
}

// ---------------- fused prep: W^T split (blocks 0..255) + msg_emb split (256..511) ----------------
__global__ void prep_kernel(const float* __restrict__ Wl, const float* __restrict__ Wr,
                            const float* __restrict__ msg, const float* __restrict__ fcW,
                            const float* __restrict__ fcb,
                            unsigned short* __restrict__ wt_hi, unsigned short* __restrict__ wt_lo,
                            unsigned short* __restrict__ mb_hi, unsigned short* __restrict__ mb_lo) {
  if (blockIdx.x < 256) {
    int c = blockIdx.x;        // output col 0..255
    int k = threadIdx.x;       // 0..127
    const float* W = (c < HCC) ? Wl : Wr;
    int cc = c & (HCC - 1);
    float v = W[(size_t)k * HCC + cc];
    unsigned short hi = f32_to_bf16(v);
    unsigned short lo = f32_to_bf16(v - bf16_to_f32(hi));
    wt_hi[(size_t)c * HCC + k] = hi;
    wt_lo[(size_t)c * HCC + k] = lo;
  } else {
    int r = blockIdx.x - 256, c = threadIdx.x;
    const float* mrow = &msg[(size_t)r * HCC];
    float acc = fcb[c];
    #pragma unroll 8
    for (int k = 0; k < HCC; k++) acc = fmaf(mrow[k], fcW[(size_t)k * HCC + c], acc);
    unsigned short hi = f32_to_bf16(acc);
    unsigned short lo = f32_to_bf16(acc - bf16_to_f32(hi));
    mb_hi[(size_t)r * HCC + c] = hi;
    mb_lo[(size_t)r * HCC + c] = lo;
  }
}

// ---------------- l2 transforms via bf16x3-split MFMA ----------------
__global__ __launch_bounds__(256) void l2_mfma_kernel(
    const unsigned short* __restrict__ h_hi, const unsigned short* __restrict__ h_lo,
    const unsigned short* __restrict__ wt_hi, const unsigned short* __restrict__ wt_lo,
    const float* __restrict__ bl, const float* __restrict__ br,
    float* __restrict__ xl, float* __restrict__ xr, int N) {
  __shared__ __align__(16) unsigned short bs[2][256][40];  // 40 KB
  int tid = threadIdx.x;
  int w = tid >> 6, lane = tid & 63;
  int g = lane >> 4, c15 = lane & 15;
  int nodeA = blockIdx.x * 64 + w * 16 + c15;
  int rA = nodeA < N ? nodeA : N - 1;

  bf16x8 ah[4], al[4];
  #pragma unroll
  for (int ks = 0; ks < 4; ks++) {
    int kb = ks * 32 + g * 8;
    ah[ks] = *reinterpret_cast<const bf16x8*>(&h_hi[(size_t)rA * HCC + kb]);
    al[ks] = *reinterpret_cast<const bf16x8*>(&h_lo[(size_t)rA * HCC + kb]);
  }

  f32x4 acc[16];
  #pragma unroll
  for (int f = 0; f < 16; f++) acc[f] = (f32x4){0.f, 0.f, 0.f, 0.f};

  #pragma unroll
  for (int ks = 0; ks < 4; ks++) {
    __syncthreads();
    #pragma unroll
    for (int j = 0; j < 8; j++) {
      int cidx = tid + 256 * j;            // 0..2047 granules of 16 B
      int a = cidx >> 10;
      int m = (cidx & 1023) >> 2;
      int gq = cidx & 3;
      const unsigned short* src = a ? wt_lo : wt_hi;
      bf16x8 v = *reinterpret_cast<const bf16x8*>(&src[(size_t)m * HCC + ks * 32 + gq * 8]);
      *reinterpret_cast<bf16x8*>(&bs[a][m][gq * 8]) = v;
    }
    __syncthreads();
    #pragma unroll
    for (int f = 0; f < 16; f++) {
      int rB = f * 16 + c15;
      bf16x8 bh = *reinterpret_cast<const bf16x8*>(&bs[0][rB][g * 8]);
      bf16x8 bv = *reinterpret_cast<const bf16x8*>(&bs[1][rB][g * 8]);
      acc[f] = __builtin_amdgcn_mfma_f32_16x16x32_bf16(ah[ks], bh, acc[f], 0, 0, 0);
      acc[f] = __builtin_amdgcn_mfma_f32_16x16x32_bf16(ah[ks], bv, acc[f], 0, 0, 0);
      acc[f] = __builtin_amdgcn_mfma_f32_16x16x32_bf16(al[ks], bh, acc[f], 0, 0, 0);
    }
  }

  float bcol[16];
  #pragma unroll
  for (int f = 0; f < 16; f++) {
    int col = f * 16 + c15;
    bcol[f] = (col < HCC) ? bl[col] : br[col - HCC];
  }

  #pragma unroll
  for (int r = 0; r < 4; r++) {
    int node = blockIdx.x * 64 + w * 16 + g * 4 + r;
    if (node < N) {
      #pragma unroll
      for (int f = 0; f < 16; f++) {
        int col = f * 16 + c15;
        float v = acc[f][r] + bcol[f];
        if (col < HCC) xl[(size_t)node * HCC + col] = v;
        else           xr[(size_t)node * HCC + col - HCC] = v;
      }
    }
  }
}

// ---------------- logits = h @ memb^T via bf16x3-split MFMA; row softmax ----------------
__global__ __launch_bounds__(256) void logits_mfma_kernel(
    const unsigned short* __restrict__ h_hi, const unsigned short* __restrict__ h_lo,
    const unsigned short* __restrict__ mb_hi, const unsigned short* __restrict__ mb_lo,
    float* __restrict__ out, int N) {
  __shared__ __align__(16) unsigned short bs[2][256][40];  // 40 KB
  int tid = threadIdx.x;
  int w = tid >> 6, lane = tid & 63;
  int g = lane >> 4, c15 = lane & 15;
  int nodeA = blockIdx.x * 64 + w * 16 + c15;
  int rA = nodeA < N ? nodeA : N - 1;

  bf16x8 ah[4], al[4];
  #pragma unroll
  for (int ks = 0; ks < 4; ks++) {
    int kb = ks * 32 + g * 8;
    ah[ks] = *reinterpret_cast<const bf16x8*>(&h_hi[(size_t)rA * HCC + kb]);
    al[ks] = *reinterpret_cast<const bf16x8*>(&h_lo[(size_t)rA * HCC + kb]);
  }

  f32x4 acc[16];
  #pragma unroll
  for (int f = 0; f < 16; f++) acc[f] = (f32x4){0.f, 0.f, 0.f, 0.f};

  #pragma unroll
  for (int ks = 0; ks < 4; ks++) {
    __syncthreads();
    #pragma unroll
    for (int j = 0; j < 8; j++) {
      int cidx = tid + 256 * j;
      int a = cidx >> 10;
      int m = (cidx & 1023) >> 2;
      int gq = cidx & 3;
      const unsigned short* src = a ? mb_lo : mb_hi;
      bf16x8 v = *reinterpret_cast<const bf16x8*>(&src[(size_t)m * HCC + ks * 32 + gq * 8]);
      *reinterpret_cast<bf16x8*>(&bs[a][m][gq * 8]) = v;
    }
    __syncthreads();
    #pragma unroll
    for (int f = 0; f < 16; f++) {
      int rB = f * 16 + c15;
      bf16x8 bh = *reinterpret_cast<const bf16x8*>(&bs[0][rB][g * 8]);
      bf16x8 bl = *reinterpret_cast<const bf16x8*>(&bs[1][rB][g * 8]);
      acc[f] = __builtin_amdgcn_mfma_f32_16x16x32_bf16(ah[ks], bh, acc[f], 0, 0, 0);
      acc[f] = __builtin_amdgcn_mfma_f32_16x16x32_bf16(ah[ks], bl, acc[f], 0, 0, 0);
      acc[f] = __builtin_amdgcn_mfma_f32_16x16x32_bf16(al[ks], bh, acc[f], 0, 0, 0);
    }
  }

  #pragma unroll
  for (int r = 0; r < 4; r++) {
    int node = blockIdx.x * 64 + w * 16 + g * 4 + r;
    float mx = acc[0][r];
    #pragma unroll
    for (int f = 1; f < 16; f++) mx = fmaxf(mx, acc[f][r]);
    #pragma unroll
    for (int off = 1; off < 16; off <<= 1) mx = fmaxf(mx, __shfl_xor(mx, off));
    float e[16], s = 0.f;
    #pragma unroll
    for (int f = 0; f < 16; f++) { e[f] = expf(acc[f][r] - mx); s += e[f]; }
    #pragma unroll
    for (int off = 1; off < 16; off <<= 1) s += __shfl_xor(s, off);
    float inv = 1.0f / s;
    if (node < N) {
      #pragma unroll
      for (int f = 0; f < 16; f++) out[(size_t)node * 256 + f * 16 + c15] = e[f] * inv;
    }
  }
}

extern "C" void kernel_launch(void* const* d_in, const int* in_sizes, int n_in,
                              void* d_out, int out_size, void* d_ws, size_t ws_size,
                              hipStream_t stream) {
  (void)n_in; (void)out_size; (void)ws_size;
  const float* message  = (const float*)d_in[0];
  const float* x        = (const float*)d_in[1];
  const float* edge_attr= (const float*)d_in[2];
  const float* c1_Wl   = (const float*)d_in[3];
  const float* c1_bl   = (const float*)d_in[4];
  const float* c1_Wr   = (const float*)d_in[5];
  const float* c1_br   = (const float*)d_in[6];
  const float* c1_We   = (const float*)d_in[7];
  const float* c1_att  = (const float*)d_in[8];
  const float* c1_bias = (const float*)d_in[9];
  const float* c2_Wl   = (const float*)d_in[10];
  const float* c2_bl   = (const float*)d_in[11];
  const float* c2_Wr   = (const float*)d_in[12];
  const float* c2_br   = (const float*)d_in[13];
  const float* c2_We   = (const float*)d_in[14];
  const float* c2_att  = (const float*)d_in[15];
  const float* c2_bias = (const float*)d_in[16];
  const float* fc1_W   = (const float*)d_in[17];
  const float* fc1_b   = (const float*)d_in[18];
  const int* edge_index = (const int*)d_in[19];

  const int N = in_sizes[1];          // 50000
  const int E = in_sizes[2];          // 500000
  const int Et = E + N;
  float* out = (float*)d_out;

  char* wsb = (char*)d_ws;
  size_t woff = 0;
  auto alloc = [&](size_t bytes) -> void* {
    void* p = wsb + woff;
    woff += (bytes + 255) & ~(size_t)255;
    return p;
  };
  float* xl     = (float*)alloc((size_t)N * HCC * 4);
  float* xr     = (float*)alloc((size_t)N * HCC * 4);
  float* hb     = (float*)alloc((size_t)N * HCC * 4);  // holds h splits (h1, then h2)
  unsigned short* mb_hi = (unsigned short*)alloc((size_t)256 * HCC * 2);
  unsigned short* mb_lo = (unsigned short*)alloc((size_t)256 * HCC * 2);
  unsigned short* wt_hi = (unsigned short*)alloc((size_t)256 * HCC * 2);
  unsigned short* wt_lo = (unsigned short*)alloc((size_t)256 * HCC * 2);
  float* ea_sum = (float*)alloc(256);
  int* deg      = (int*)alloc((size_t)N * 4);
  int* offs     = (int*)alloc((size_t)(N + 1) * 4);
  int* bsum     = (int*)alloc(256 * 4);
  int* cursor   = (int*)alloc((size_t)N * 4);
  int2* csr_pack= (int2*)alloc((size_t)Et * 8);

  unsigned short* h_hi = (unsigned short*)hb;
  unsigned short* h_lo = h_hi + (size_t)N * HCC;

  const int NB = (N + 1023) / 1024;   // 49 blocks (<=64 required)

  init_kernel<<<(N + 256) / 256, 256, 0, stream>>>(deg, cursor, ea_sum, N);
  eadeg_kernel<<<(Et + 255) / 256, 256, 0, stream>>>(edge_index, edge_attr, deg, ea_sum, E, N);
  blocksum_kernel<<<NB, 1024, 0, stream>>>(deg, bsum, N);
  scanfinal_kernel<<<NB, 1024, 0, stream>>>(deg, bsum, offs, N, NB);
  scatter_kernel<<<(Et + 255) / 256, 256, 0, stream>>>(edge_index, edge_attr, ea_sum,
                                                       offs, cursor, csr_pack, E, N);
  prep_kernel<<<512, 128, 0, stream>>>(c2_Wl, c2_Wr, message, fc1_W, fc1_b,
                                       wt_hi, wt_lo, mb_hi, mb_lo);
  gat1_kernel<<<(N + 3) / 4, 256, 0, stream>>>(x, offs, csr_pack,
                                               c1_Wl, c1_bl, c1_Wr, c1_br,
                                               c1_We, c1_att, c1_bias, h_hi, h_lo, N);
  l2_mfma_kernel<<<(N + 63) / 64, 256, 0, stream>>>(h_hi, h_lo, wt_hi, wt_lo,
                                                    c2_bl, c2_br, xl, xr, N);
  gat2_kernel<<<(N + 3) / 4, 256, 0, stream>>>(xl, xr, offs, csr_pack,
                                               c2_We, c2_att, c2_bias, h_hi, h_lo, N);
  logits_mfma_kernel<<<(N + 63) / 64, 256, 0, stream>>>(h_hi, h_lo, mb_hi, mb_lo, out, N);
}

// Round 12
// 216.979 us; speedup vs baseline: 1.4032x; 1.4032x over previous
//
#include <hip/hip_runtime.h>

#define HCC 128
#define NEG_SLOPE 0.2f
#define CHUNK 16

using bf16x8 = __attribute__((ext_vector_type(8))) __bf16;
using f32x4  = __attribute__((ext_vector_type(4))) float;

__device__ inline unsigned short f32_to_bf16(float v) {
  unsigned u = __float_as_uint(v);
  unsigned r = u + 0x7FFFu + ((u >> 16) & 1u);
  return (unsigned short)(r >> 16);
}
__device__ inline float bf16_to_f32(unsigned short h) {
  return __uint_as_float(((unsigned)h) << 16);
}

// fold-reduce step: k simultaneous 32-lane reductions, halving per step.
#define FOLD_STEP(S, CNT)                                    \
  {                                                          \
    _Pragma("unroll")                                        \
    for (int q = 0; q < CNT; q++) {                          \
      bool hi = (lane & S) != 0;                             \
      float give = hi ? pr[q] : pr[q + CNT];                 \
      float keep = hi ? pr[q + CNT] : pr[q];                 \
      pr[q] = keep + __shfl_xor(give, S);                    \
    }                                                        \
  }

// ---------------- init: zero deg, cursor, ea_sum (replaces 3 memsets) ----------------
__global__ void init_kernel(int* __restrict__ deg, int* __restrict__ cursor,
                            float* __restrict__ ea_sum, int N) {
  int i = blockIdx.x * blockDim.x + threadIdx.x;
  if (i < N) { deg[i] = 0; cursor[i] = 0; }
  if (i == N) ea_sum[0] = 0.f;
}

// ---------------- edge_attr sum: 256 blocks, ONE atomic per block ----------------
__global__ void ea_reduce_kernel(const float* __restrict__ ea, float* __restrict__ sum, int E) {
  __shared__ float ws[4];
  float acc = 0.f;
  for (int i = blockIdx.x * blockDim.x + threadIdx.x; i < E; i += gridDim.x * blockDim.x)
    acc += ea[i];
  #pragma unroll
  for (int off = 32; off > 0; off >>= 1) acc += __shfl_down(acc, off);
  if ((threadIdx.x & 63) == 0) ws[threadIdx.x >> 6] = acc;
  __syncthreads();
  if (threadIdx.x == 0)
    atomicAdd(sum, (ws[0] + ws[1]) + (ws[2] + ws[3]));
}

// ---------------- degree count (distributed int atomics — fast) ----------------
__global__ void deg_count_kernel(const int* __restrict__ ei, int* __restrict__ deg, int E, int N) {
  int k = blockIdx.x * blockDim.x + threadIdx.x;
  if (k >= E + N) return;
  int t = (k < E) ? ei[E + k] : (k - E);
  atomicAdd(&deg[t], 1);
}

// ---------------- per-1024-block sums ----------------
__global__ __launch_bounds__(1024) void blocksum_kernel(const int* __restrict__ deg,
                                                        int* __restrict__ bsum, int n) {
  __shared__ int ws[16];
  int i = blockIdx.x * 1024 + threadIdx.x;
  int v = (i < n) ? deg[i] : 0;
  int lane = threadIdx.x & 63, wid = threadIdx.x >> 6;
  #pragma unroll
  for (int off = 32; off > 0; off >>= 1) v += __shfl_xor(v, off);
  if (lane == 0) ws[wid] = v;
  __syncthreads();
  if (threadIdx.x < 16) {
    int t = ws[threadIdx.x];
    #pragma unroll
    for (int off = 8; off > 0; off >>= 1) t += __shfl_xor(t, off);
    if (threadIdx.x == 0) bsum[blockIdx.x] = t;
  }
}

// ---------------- final scan: every block wave-scans bsum (<=64) itself ----------------
__global__ __launch_bounds__(1024) void scanfinal_kernel(const int* __restrict__ deg,
    const int* __restrict__ bsum, int* __restrict__ offs, int n, int nb) {
  __shared__ int wsum[16];
  __shared__ int bbase, btot;
  int tid = threadIdx.x;
  if (tid < 64) {
    int v = (tid < nb) ? bsum[tid] : 0;
    int x = v;
    #pragma unroll
    for (int off = 1; off < 64; off <<= 1) {
      int y = __shfl_up(x, off);
      if (tid >= off) x += y;
    }
    if (tid == (int)blockIdx.x) bbase = x - v;  // exclusive base of this block
    if (tid == 63) btot = x;
  }
  __syncthreads();
  int i = blockIdx.x * 1024 + tid;
  int v = (i < n) ? deg[i] : 0;
  int lane = tid & 63, wid = tid >> 6;
  int x = v;
  #pragma unroll
  for (int off = 1; off < 64; off <<= 1) {
    int y = __shfl_up(x, off);
    if (lane >= off) x += y;
  }
  if (lane == 63) wsum[wid] = x;
  __syncthreads();
  if (tid < 16) {
    int t = wsum[tid];
    int s = t;
    #pragma unroll
    for (int off = 1; off < 16; off <<= 1) {
      int y = __shfl_up(s, off);
      if (tid >= off) s += y;
    }
    wsum[tid] = s - t;   // exclusive
  }
  __syncthreads();
  if (i < n) offs[i] = bbase + wsum[wid] + x - v;
  if (blockIdx.x == 0 && tid == 0) offs[n] = btot;
}

// ---------------- scatter edges into CSR-by-target (packed src+ea) ----------------
__global__ void scatter_kernel(const int* __restrict__ ei, const float* __restrict__ ea,
                               const float* __restrict__ ea_sum, const int* __restrict__ offs,
                               int* __restrict__ cursor, int2* __restrict__ csr_pack,
                               int E, int N) {
  int k = blockIdx.x * blockDim.x + threadIdx.x;
  if (k >= E + N) return;
  int s, t; float v;
  if (k < E) { s = ei[k]; t = ei[E + k]; v = ea[k]; }
  else       { s = t = k - E; v = ea_sum[0] * (1.0f / (float)E); }
  int pos = offs[t] + atomicAdd(&cursor[t], 1);
  csr_pack[pos] = make_int2(s, __float_as_int(v));
}

// ---------------- GATv2 layer 1, specialized for x of shape (N,1) ----------------
__global__ void gat1_kernel(const float* __restrict__ x,
    const int* __restrict__ offs, const int2* __restrict__ csr_pack,
    const float* __restrict__ Wl, const float* __restrict__ bl,
    const float* __restrict__ Wr, const float* __restrict__ br,
    const float* __restrict__ We, const float* __restrict__ att,
    const float* __restrict__ bias,
    unsigned short* __restrict__ h_hi, unsigned short* __restrict__ h_lo, int N) {
  int t = (blockIdx.x * blockDim.x + threadIdx.x) >> 6;
  if (t >= N) return;
  int lane = threadIdx.x & 63;
  int c = lane * 2;
  float2 wl = *(const float2*)&Wl[c];
  float2 wr = *(const float2*)&Wr[c];
  float2 we = *(const float2*)&We[c];
  float2 at = *(const float2*)&att[c];
  float2 bl2 = *(const float2*)&bl[c];
  float2 br2 = *(const float2*)&br[c];
  float xt = x[t];
  float base0 = fmaf(xt, wr.x, br2.x + bl2.x);
  float base1 = fmaf(xt, wr.y, br2.y + bl2.y);
  int e0 = offs[t], e1 = offs[t + 1];
  int qlane = (lane >> 1) & 15;
  int bb = lane & 32;

  float den = 0.f, S1 = 0.f;
  for (int base = e0; base < e1; base += CHUNK) {
    int eidx = base + (lane & 15);
    eidx = eidx < e1 ? eidx : e1 - 1;
    int2 pk = csr_pack[eidx];
    float xs[CHUNK], eav[CHUNK];
    #pragma unroll
    for (int q = 0; q < CHUNK; q++) {
      int s = __builtin_amdgcn_readlane(pk.x, q);
      eav[q] = __uint_as_float(__builtin_amdgcn_readlane(pk.y, q));
      xs[q] = x[s];
    }
    float pr[CHUNK];
    #pragma unroll
    for (int q = 0; q < CHUNK; q++) {
      float m0 = fmaf(xs[q], wl.x, fmaf(eav[q], we.x, base0));
      float m1 = fmaf(xs[q], wl.y, fmaf(eav[q], we.y, base1));
      float l0 = fmaxf(m0, NEG_SLOPE * m0);
      float l1 = fmaxf(m1, NEG_SLOPE * m1);
      pr[q] = fmaf(l0, at.x, l1 * at.y);
    }
    FOLD_STEP(16, 8) FOLD_STEP(8, 4) FOLD_STEP(4, 2) FOLD_STEP(2, 1)
    pr[0] += __shfl_xor(pr[0], 1);
    float wgt = (base + qlane < e1) ? __expf(pr[0]) : 0.f;
    // den via HALF-wave reduction (off<32 never crosses the head boundary):
    // within a 32-lane half each edge's wgt lives in exactly 2 lanes.
    float ws = wgt;
    #pragma unroll
    for (int off = 1; off < 32; off <<= 1) ws += __shfl_xor(ws, off);
    den = fmaf(ws, 0.5f, den);
    #pragma unroll
    for (int q = 0; q < CHUNK; q++) {
      float wq = __shfl(wgt, bb + 2 * q);
      S1 = fmaf(wq, xs[q], S1);
    }
  }
  float T = S1 / den;
  float2 bv = *(const float2*)&bias[c];
  float o0 = fmaxf(fmaf(wl.x, T, bl2.x + bv.x), 0.f);
  float o1 = fmaxf(fmaf(wl.y, T, bl2.y + bv.y), 0.f);
  unsigned short hh0 = f32_to_bf16(o0);
  unsigned short hl0 = f32_to_bf16(o0 - bf16_to_f32(hh0));
  unsigned short hh1 = f32_to_bf16(o1);
  unsigned short hl1 = f32_to_bf16(o1 - bf16_to_f32(hh1));
  *(ushort2*)&h_hi[(size_t)t * HCC + c] = make_ushort2(hh0, hh1);
  *(ushort2*)&h_lo[(size_t)t * HCC + c] = make_ushort2(hl0, hl1);
}

// ---------------- GATv2 layer 2: one wave per node ----------------
__global__ void gat2_kernel(const float* __restrict__ xl, const float* __restrict__ xr,
    const int* __restrict__ offs, const int2* __restrict__ csr_pack,
    const float* __restrict__ We, const float* __restrict__ att,
    const float* __restrict__ bias,
    unsigned short* __restrict__ h_hi, unsigned short* __restrict__ h_lo, int N) {
  int t = (blockIdx.x * blockDim.x + threadIdx.x) >> 6;
  if (t >= N) return;
  int lane = threadIdx.x & 63;
  int c = lane * 2;
  float2 xrv = *(const float2*)&xr[(size_t)t * HCC + c];
  float2 wev = *(const float2*)&We[c];
  float2 atv = *(const float2*)&att[c];
  int e0 = offs[t], e1 = offs[t + 1];
  int qlane = (lane >> 1) & 15;
  int bb = lane & 32;

  float den = 0.f, a0 = 0.f, a1 = 0.f;
  for (int base = e0; base < e1; base += CHUNK) {
    int eidx = base + (lane & 15);
    eidx = eidx < e1 ? eidx : e1 - 1;
    int2 pk = csr_pack[eidx];                 // 1 VMEM for all 16 edges
    float2 xj[CHUNK];
    #pragma unroll
    for (int q = 0; q < CHUNK; q++) {
      int s = __builtin_amdgcn_readlane(pk.x, q);
      xj[q] = *(const float2*)&xl[(size_t)s * HCC + c];
    }
    float pr[CHUNK];
    #pragma unroll
    for (int q = 0; q < CHUNK; q++) {
      float eav = __uint_as_float(__builtin_amdgcn_readlane(pk.y, q));
      float m0 = fmaf(eav, wev.x, xrv.x + xj[q].x);
      float m1 = fmaf(eav, wev.y, xrv.y + xj[q].y);
      float l0 = fmaxf(m0, NEG_SLOPE * m0);
      float l1 = fmaxf(m1, NEG_SLOPE * m1);
      pr[q] = fmaf(l0, atv.x, l1 * atv.y);
    }
    FOLD_STEP(16, 8) FOLD_STEP(8, 4) FOLD_STEP(4, 2) FOLD_STEP(2, 1)
    pr[0] += __shfl_xor(pr[0], 1);
    float wgt = (base + qlane < e1) ? __expf(pr[0]) : 0.f;
    // HALF-wave reduction: head-local denominator (2 lanes per edge per half)
    float ws = wgt;
    #pragma unroll
    for (int off = 1; off < 32; off <<= 1) ws += __shfl_xor(ws, off);
    den = fmaf(ws, 0.5f, den);
    #pragma unroll
    for (int q = 0; q < CHUNK; q++) {
      float wq = __shfl(wgt, bb + 2 * q);
      a0 = fmaf(wq, xj[q].x, a0);
      a1 = fmaf(wq, xj[q].y, a1);
    }
  }
  float inv = 1.0f / den;
  float2 bv = *(const float2*)&bias[c];
  float o0 = fmaxf(fmaf(a0, inv, bv.x), 0.f);
  float o1 = fmaxf(fmaf(a1, inv, bv.y), 0.f);
  unsigned short hh0 = f32_to_bf16(o0);
  unsigned short hl0 = f32_to_bf16(o0 - bf16_to_f32(hh0));
  unsigned short hh1 = f32_to_bf16(o1);
  unsigned short hl1 = f32_to_bf16(o1 - bf16_to_f32(hh1));
  *(ushort2*)&h_hi[(size_t)t * HCC + c] = make_ushort2(hh0, hh1);
  *(ushort2*)&h_lo[(size_t)t * HCC + c] = make_ushort2(hl0, hl1);
}

// ---------------- fused prep: W^T split (blocks 0..255) + msg_emb split (256..511) ----------------
__global__ void prep_kernel(const float* __restrict__ Wl, const float* __restrict__ Wr,
                            const float* __restrict__ msg, const float* __restrict__ fcW,
                            const float* __restrict__ fcb,
                            unsigned short* __restrict__ wt_hi, unsigned short* __restrict__ wt_lo,
                            unsigned short* __restrict__ mb_hi, unsigned short* __restrict__ mb_lo) {
  if (blockIdx.x < 256) {
    int c = blockIdx.x;        // output col 0..255
    int k = threadIdx.x;       // 0..127
    const float* W = (c < HCC) ? Wl : Wr;
    int cc = c & (HCC - 1);
    float v = W[(size_t)k * HCC + cc];
    unsigned short hi = f32_to_bf16(v);
    unsigned short lo = f32_to_bf16(v - bf16_to_f32(hi));
    wt_hi[(size_t)c * HCC + k] = hi;
    wt_lo[(size_t)c * HCC + k] = lo;
  } else {
    int r = blockIdx.x - 256, c = threadIdx.x;
    const float* mrow = &msg[(size_t)r * HCC];
    float acc = fcb[c];
    #pragma unroll 8
    for (int k = 0; k < HCC; k++) acc = fmaf(mrow[k], fcW[(size_t)k * HCC + c], acc);
    unsigned short hi = f32_to_bf16(acc);
    unsigned short lo = f32_to_bf16(acc - bf16_to_f32(hi));
    mb_hi[(size_t)r * HCC + c] = hi;
    mb_lo[(size_t)r * HCC + c] = lo;
  }
}

// ---------------- l2 transforms via bf16x3-split MFMA ----------------
__global__ __launch_bounds__(256) void l2_mfma_kernel(
    const unsigned short* __restrict__ h_hi, const unsigned short* __restrict__ h_lo,
    const unsigned short* __restrict__ wt_hi, const unsigned short* __restrict__ wt_lo,
    const float* __restrict__ bl, const float* __restrict__ br,
    float* __restrict__ xl, float* __restrict__ xr, int N) {
  __shared__ __align__(16) unsigned short bs[2][256][40];  // 40 KB
  int tid = threadIdx.x;
  int w = tid >> 6, lane = tid & 63;
  int g = lane >> 4, c15 = lane & 15;
  int nodeA = blockIdx.x * 64 + w * 16 + c15;
  int rA = nodeA < N ? nodeA : N - 1;

  bf16x8 ah[4], al[4];
  #pragma unroll
  for (int ks = 0; ks < 4; ks++) {
    int kb = ks * 32 + g * 8;
    ah[ks] = *reinterpret_cast<const bf16x8*>(&h_hi[(size_t)rA * HCC + kb]);
    al[ks] = *reinterpret_cast<const bf16x8*>(&h_lo[(size_t)rA * HCC + kb]);
  }

  f32x4 acc[16];
  #pragma unroll
  for (int f = 0; f < 16; f++) acc[f] = (f32x4){0.f, 0.f, 0.f, 0.f};

  #pragma unroll
  for (int ks = 0; ks < 4; ks++) {
    __syncthreads();
    #pragma unroll
    for (int j = 0; j < 8; j++) {
      int cidx = tid + 256 * j;            // 0..2047 granules of 16 B
      int a = cidx >> 10;
      int m = (cidx & 1023) >> 2;
      int gq = cidx & 3;
      const unsigned short* src = a ? wt_lo : wt_hi;
      bf16x8 v = *reinterpret_cast<const bf16x8*>(&src[(size_t)m * HCC + ks * 32 + gq * 8]);
      *reinterpret_cast<bf16x8*>(&bs[a][m][gq * 8]) = v;
    }
    __syncthreads();
    #pragma unroll
    for (int f = 0; f < 16; f++) {
      int rB = f * 16 + c15;
      bf16x8 bh = *reinterpret_cast<const bf16x8*>(&bs[0][rB][g * 8]);
      bf16x8 bv = *reinterpret_cast<const bf16x8*>(&bs[1][rB][g * 8]);
      acc[f] = __builtin_amdgcn_mfma_f32_16x16x32_bf16(ah[ks], bh, acc[f], 0, 0, 0);
      acc[f] = __builtin_amdgcn_mfma_f32_16x16x32_bf16(ah[ks], bv, acc[f], 0, 0, 0);
      acc[f] = __builtin_amdgcn_mfma_f32_16x16x32_bf16(al[ks], bh, acc[f], 0, 0, 0);
    }
  }

  float bcol[16];
  #pragma unroll
  for (int f = 0; f < 16; f++) {
    int col = f * 16 + c15;
    bcol[f] = (col < HCC) ? bl[col] : br[col - HCC];
  }

  #pragma unroll
  for (int r = 0; r < 4; r++) {
    int node = blockIdx.x * 64 + w * 16 + g * 4 + r;
    if (node < N) {
      #pragma unroll
      for (int f = 0; f < 16; f++) {
        int col = f * 16 + c15;
        float v = acc[f][r] + bcol[f];
        if (col < HCC) xl[(size_t)node * HCC + col] = v;
        else           xr[(size_t)node * HCC + col - HCC] = v;
      }
    }
  }
}

// ---------------- logits = h @ memb^T via bf16x3-split MFMA; row softmax ----------------
__global__ __launch_bounds__(256) void logits_mfma_kernel(
    const unsigned short* __restrict__ h_hi, const unsigned short* __restrict__ h_lo,
    const unsigned short* __restrict__ mb_hi, const unsigned short* __restrict__ mb_lo,
    float* __restrict__ out, int N) {
  __shared__ __align__(16) unsigned short bs[2][256][40];  // 40 KB
  int tid = threadIdx.x;
  int w = tid >> 6, lane = tid & 63;
  int g = lane >> 4, c15 = lane & 15;
  int nodeA = blockIdx.x * 64 + w * 16 + c15;
  int rA = nodeA < N ? nodeA : N - 1;

  bf16x8 ah[4], al[4];
  #pragma unroll
  for (int ks = 0; ks < 4; ks++) {
    int kb = ks * 32 + g * 8;
    ah[ks] = *reinterpret_cast<const bf16x8*>(&h_hi[(size_t)rA * HCC + kb]);
    al[ks] = *reinterpret_cast<const bf16x8*>(&h_lo[(size_t)rA * HCC + kb]);
  }

  f32x4 acc[16];
  #pragma unroll
  for (int f = 0; f < 16; f++) acc[f] = (f32x4){0.f, 0.f, 0.f, 0.f};

  #pragma unroll
  for (int ks = 0; ks < 4; ks++) {
    __syncthreads();
    #pragma unroll
    for (int j = 0; j < 8; j++) {
      int cidx = tid + 256 * j;
      int a = cidx >> 10;
      int m = (cidx & 1023) >> 2;
      int gq = cidx & 3;
      const unsigned short* src = a ? mb_lo : mb_hi;
      bf16x8 v = *reinterpret_cast<const bf16x8*>(&src[(size_t)m * HCC + ks * 32 + gq * 8]);
      *reinterpret_cast<bf16x8*>(&bs[a][m][gq * 8]) = v;
    }
    __syncthreads();
    #pragma unroll
    for (int f = 0; f < 16; f++) {
      int rB = f * 16 + c15;
      bf16x8 bh = *reinterpret_cast<const bf16x8*>(&bs[0][rB][g * 8]);
      bf16x8 bl = *reinterpret_cast<const bf16x8*>(&bs[1][rB][g * 8]);
      acc[f] = __builtin_amdgcn_mfma_f32_16x16x32_bf16(ah[ks], bh, acc[f], 0, 0, 0);
      acc[f] = __builtin_amdgcn_mfma_f32_16x16x32_bf16(ah[ks], bl, acc[f], 0, 0, 0);
      acc[f] = __builtin_amdgcn_mfma_f32_16x16x32_bf16(al[ks], bh, acc[f], 0, 0, 0);
    }
  }

  #pragma unroll
  for (int r = 0; r < 4; r++) {
    int node = blockIdx.x * 64 + w * 16 + g * 4 + r;
    float mx = acc[0][r];
    #pragma unroll
    for (int f = 1; f < 16; f++) mx = fmaxf(mx, acc[f][r]);
    #pragma unroll
    for (int off = 1; off < 16; off <<= 1) mx = fmaxf(mx, __shfl_xor(mx, off));
    float e[16], s = 0.f;
    #pragma unroll
    for (int f = 0; f < 16; f++) { e[f] = expf(acc[f][r] - mx); s += e[f]; }
    #pragma unroll
    for (int off = 1; off < 16; off <<= 1) s += __shfl_xor(s, off);
    float inv = 1.0f / s;
    if (node < N) {
      #pragma unroll
      for (int f = 0; f < 16; f++) out[(size_t)node * 256 + f * 16 + c15] = e[f] * inv;
    }
  }
}

extern "C" void kernel_launch(void* const* d_in, const int* in_sizes, int n_in,
                              void* d_out, int out_size, void* d_ws, size_t ws_size,
                              hipStream_t stream) {
  (void)n_in; (void)out_size; (void)ws_size;
  const float* message  = (const float*)d_in[0];
  const float* x        = (const float*)d_in[1];
  const float* edge_attr= (const float*)d_in[2];
  const float* c1_Wl   = (const float*)d_in[3];
  const float* c1_bl   = (const float*)d_in[4];
  const float* c1_Wr   = (const float*)d_in[5];
  const float* c1_br   = (const float*)d_in[6];
  const float* c1_We   = (const float*)d_in[7];
  const float* c1_att  = (const float*)d_in[8];
  const float* c1_bias = (const float*)d_in[9];
  const float* c2_Wl   = (const float*)d_in[10];
  const float* c2_bl   = (const float*)d_in[11];
  const float* c2_Wr   = (const float*)d_in[12];
  const float* c2_br   = (const float*)d_in[13];
  const float* c2_We   = (const float*)d_in[14];
  const float* c2_att  = (const float*)d_in[15];
  const float* c2_bias = (const float*)d_in[16];
  const float* fc1_W   = (const float*)d_in[17];
  const float* fc1_b   = (const float*)d_in[18];
  const int* edge_index = (const int*)d_in[19];

  const int N = in_sizes[1];          // 50000
  const int E = in_sizes[2];          // 500000
  const int Et = E + N;
  float* out = (float*)d_out;

  char* wsb = (char*)d_ws;
  size_t woff = 0;
  auto alloc = [&](size_t bytes) -> void* {
    void* p = wsb + woff;
    woff += (bytes + 255) & ~(size_t)255;
    return p;
  };
  float* xl     = (float*)alloc((size_t)N * HCC * 4);
  float* xr     = (float*)alloc((size_t)N * HCC * 4);
  float* hb     = (float*)alloc((size_t)N * HCC * 4);  // holds h splits (h1, then h2)
  unsigned short* mb_hi = (unsigned short*)alloc((size_t)256 * HCC * 2);
  unsigned short* mb_lo = (unsigned short*)alloc((size_t)256 * HCC * 2);
  unsigned short* wt_hi = (unsigned short*)alloc((size_t)256 * HCC * 2);
  unsigned short* wt_lo = (unsigned short*)alloc((size_t)256 * HCC * 2);
  float* ea_sum = (float*)alloc(256);
  int* deg      = (int*)alloc((size_t)N * 4);
  int* offs     = (int*)alloc((size_t)(N + 1) * 4);
  int* bsum     = (int*)alloc(256 * 4);
  int* cursor   = (int*)alloc((size_t)N * 4);
  int2* csr_pack= (int2*)alloc((size_t)Et * 8);

  unsigned short* h_hi = (unsigned short*)hb;
  unsigned short* h_lo = h_hi + (size_t)N * HCC;

  const int NB = (N + 1023) / 1024;   // 49 blocks (<=64 required)

  init_kernel<<<(N + 256) / 256, 256, 0, stream>>>(deg, cursor, ea_sum, N);
  ea_reduce_kernel<<<256, 256, 0, stream>>>(edge_attr, ea_sum, E);
  deg_count_kernel<<<(Et + 255) / 256, 256, 0, stream>>>(edge_index, deg, E, N);
  blocksum_kernel<<<NB, 1024, 0, stream>>>(deg, bsum, N);
  scanfinal_kernel<<<NB, 1024, 0, stream>>>(deg, bsum, offs, N, NB);
  scatter_kernel<<<(Et + 255) / 256, 256, 0, stream>>>(edge_index, edge_attr, ea_sum,
                                                       offs, cursor, csr_pack, E, N);
  prep_kernel<<<512, 128, 0, stream>>>(c2_Wl, c2_Wr, message, fc1_W, fc1_b,
                                       wt_hi, wt_lo, mb_hi, mb_lo);
  gat1_kernel<<<(N + 3) / 4, 256, 0, stream>>>(x, offs, csr_pack,
                                               c1_Wl, c1_bl, c1_Wr, c1_br,
                                               c1_We, c1_att, c1_bias, h_hi, h_lo, N);
  l2_mfma_kernel<<<(N + 63) / 64, 256, 0, stream>>>(h_hi, h_lo, wt_hi, wt_lo,
                                                    c2_bl, c2_br, xl, xr, N);
  gat2_kernel<<<(N + 3) / 4, 256, 0, stream>>>(xl, xr, offs, csr_pack,
                                               c2_We, c2_att, c2_bias, h_hi, h_lo, N);
  logits_mfma_kernel<<<(N + 63) / 64, 256, 0, stream>>>(h_hi, h_lo, mb_hi, mb_lo, out, N);
}

// Round 13
// 213.766 us; speedup vs baseline: 1.4243x; 1.0150x over previous
//
#include <hip/hip_runtime.h>

#define HCC 128
#define NEG_SLOPE 0.2f
#define CHUNK 16

using bf16x8 = __attribute__((ext_vector_type(8))) __bf16;
using f32x4  = __attribute__((ext_vector_type(4))) float;

__device__ inline unsigned short f32_to_bf16(float v) {
  unsigned u = __float_as_uint(v);
  unsigned r = u + 0x7FFFu + ((u >> 16) & 1u);
  return (unsigned short)(r >> 16);
}
__device__ inline float bf16_to_f32(unsigned short h) {
  return __uint_as_float(((unsigned)h) << 16);
}

// fold-reduce step: k simultaneous 32-lane reductions, halving per step.
#define FOLD_STEP(S, CNT)                                    \
  {                                                          \
    _Pragma("unroll")                                        \
    for (int q = 0; q < CNT; q++) {                          \
      bool hi = (lane & S) != 0;                             \
      float give = hi ? pr[q] : pr[q + CNT];                 \
      float keep = hi ? pr[q + CNT] : pr[q];                 \
      pr[q] = keep + __shfl_xor(give, S);                    \
    }                                                        \
  }

// ---------------- init: zero deg, cursor, ea_sum (replaces 3 memsets) ----------------
__global__ void init_kernel(int* __restrict__ deg, int* __restrict__ cursor,
                            float* __restrict__ ea_sum, int N) {
  int i = blockIdx.x * blockDim.x + threadIdx.x;
  if (i < N) { deg[i] = 0; cursor[i] = 0; }
  if (i == N) ea_sum[0] = 0.f;
}

// ---------------- edge_attr sum: 256 blocks, ONE atomic per block ----------------
__global__ void ea_reduce_kernel(const float* __restrict__ ea, float* __restrict__ sum, int E) {
  __shared__ float ws[4];
  float acc = 0.f;
  for (int i = blockIdx.x * blockDim.x + threadIdx.x; i < E; i += gridDim.x * blockDim.x)
    acc += ea[i];
  #pragma unroll
  for (int off = 32; off > 0; off >>= 1) acc += __shfl_down(acc, off);
  if ((threadIdx.x & 63) == 0) ws[threadIdx.x >> 6] = acc;
  __syncthreads();
  if (threadIdx.x == 0)
    atomicAdd(sum, (ws[0] + ws[1]) + (ws[2] + ws[3]));
}

// ---------------- degree count (distributed int atomics — fast) ----------------
__global__ void deg_count_kernel(const int* __restrict__ ei, int* __restrict__ deg, int E, int N) {
  int k = blockIdx.x * blockDim.x + threadIdx.x;
  if (k >= E + N) return;
  int t = (k < E) ? ei[E + k] : (k - E);
  atomicAdd(&deg[t], 1);
}

// ---------------- per-1024-block sums ----------------
__global__ __launch_bounds__(1024) void blocksum_kernel(const int* __restrict__ deg,
                                                        int* __restrict__ bsum, int n) {
  __shared__ int ws[16];
  int i = blockIdx.x * 1024 + threadIdx.x;
  int v = (i < n) ? deg[i] : 0;
  int lane = threadIdx.x & 63, wid = threadIdx.x >> 6;
  #pragma unroll
  for (int off = 32; off > 0; off >>= 1) v += __shfl_xor(v, off);
  if (lane == 0) ws[wid] = v;
  __syncthreads();
  if (threadIdx.x < 16) {
    int t = ws[threadIdx.x];
    #pragma unroll
    for (int off = 8; off > 0; off >>= 1) t += __shfl_xor(t, off);
    if (threadIdx.x == 0) bsum[blockIdx.x] = t;
  }
}

// ---------------- final scan: every block wave-scans bsum (<=64) itself ----------------
__global__ __launch_bounds__(1024) void scanfinal_kernel(const int* __restrict__ deg,
    const int* __restrict__ bsum, int* __restrict__ offs, int n, int nb) {
  __shared__ int wsum[16];
  __shared__ int bbase, btot;
  int tid = threadIdx.x;
  if (tid < 64) {
    int v = (tid < nb) ? bsum[tid] : 0;
    int x = v;
    #pragma unroll
    for (int off = 1; off < 64; off <<= 1) {
      int y = __shfl_up(x, off);
      if (tid >= off) x += y;
    }
    if (tid == (int)blockIdx.x) bbase = x - v;  // exclusive base of this block
    if (tid == 63) btot = x;
  }
  __syncthreads();
  int i = blockIdx.x * 1024 + tid;
  int v = (i < n) ? deg[i] : 0;
  int lane = tid & 63, wid = tid >> 6;
  int x = v;
  #pragma unroll
  for (int off = 1; off < 64; off <<= 1) {
    int y = __shfl_up(x, off);
    if (lane >= off) x += y;
  }
  if (lane == 63) wsum[wid] = x;
  __syncthreads();
  if (tid < 16) {
    int t = wsum[tid];
    int s = t;
    #pragma unroll
    for (int off = 1; off < 16; off <<= 1) {
      int y = __shfl_up(s, off);
      if (tid >= off) s += y;
    }
    wsum[tid] = s - t;   // exclusive
  }
  __syncthreads();
  if (i < n) offs[i] = bbase + wsum[wid] + x - v;
  if (blockIdx.x == 0 && tid == 0) offs[n] = btot;
}

// ---------------- scatter edges into CSR-by-target (packed src+ea) ----------------
__global__ void scatter_kernel(const int* __restrict__ ei, const float* __restrict__ ea,
                               const float* __restrict__ ea_sum, const int* __restrict__ offs,
                               int* __restrict__ cursor, int2* __restrict__ csr_pack,
                               int E, int N) {
  int k = blockIdx.x * blockDim.x + threadIdx.x;
  if (k >= E + N) return;
  int s, t; float v;
  if (k < E) { s = ei[k]; t = ei[E + k]; v = ea[k]; }
  else       { s = t = k - E; v = ea_sum[0] * (1.0f / (float)E); }
  int pos = offs[t] + atomicAdd(&cursor[t], 1);
  csr_pack[pos] = make_int2(s, __float_as_int(v));
}

// ---------------- GATv2 layer 1, specialized for x of shape (N,1) ----------------
// CSR walk entirely on the scalar pipe: edge indices are SGPR (s_min clamp),
// csr_pack reads are s_load, x[s] is s_load. Zero VALU in the load phase.
__global__ void gat1_kernel(const float* __restrict__ x,
    const int* __restrict__ offs, const int2* __restrict__ csr_pack,
    const float* __restrict__ Wl, const float* __restrict__ bl,
    const float* __restrict__ Wr, const float* __restrict__ br,
    const float* __restrict__ We, const float* __restrict__ att,
    const float* __restrict__ bias,
    unsigned short* __restrict__ h_hi, unsigned short* __restrict__ h_lo, int N) {
  int t = (blockIdx.x * blockDim.x + threadIdx.x) >> 6;
  if (t >= N) return;
  int lane = threadIdx.x & 63;
  int c = lane * 2;
  float2 wl = *(const float2*)&Wl[c];
  float2 wr = *(const float2*)&Wr[c];
  float2 we = *(const float2*)&We[c];
  float2 at = *(const float2*)&att[c];
  float2 bl2 = *(const float2*)&bl[c];
  float2 br2 = *(const float2*)&br[c];
  float xt = x[t];
  float base0 = fmaf(xt, wr.x, br2.x + bl2.x);
  float base1 = fmaf(xt, wr.y, br2.y + bl2.y);
  int e0s = __builtin_amdgcn_readfirstlane(offs[t]);
  int e1s = __builtin_amdgcn_readfirstlane(offs[t + 1]);
  int qlane = (lane >> 1) & 15;
  int bb = lane & 32;

  float den = 0.f, S1 = 0.f;
  for (int base = e0s; base < e1s; base += CHUNK) {
    float xs[CHUNK], eav[CHUNK];
    #pragma unroll
    for (int q = 0; q < CHUNK; q++) {
      int ec = base + q;                   // SGPR arithmetic
      ec = ec < e1s ? ec : e1s - 1;        // s_cselect clamp
      int2 pk = csr_pack[ec];              // s_load_dwordx2
      int s = __builtin_amdgcn_readfirstlane(pk.x);
      eav[q] = __uint_as_float(__builtin_amdgcn_readfirstlane(pk.y));
      xs[q] = x[s];                        // s_load
    }
    float pr[CHUNK];
    #pragma unroll
    for (int q = 0; q < CHUNK; q++) {
      float m0 = fmaf(xs[q], wl.x, fmaf(eav[q], we.x, base0));
      float m1 = fmaf(xs[q], wl.y, fmaf(eav[q], we.y, base1));
      float l0 = fmaxf(m0, NEG_SLOPE * m0);
      float l1 = fmaxf(m1, NEG_SLOPE * m1);
      pr[q] = fmaf(l0, at.x, l1 * at.y);
    }
    FOLD_STEP(16, 8) FOLD_STEP(8, 4) FOLD_STEP(4, 2) FOLD_STEP(2, 1)
    pr[0] += __shfl_xor(pr[0], 1);
    float wgt = (base + qlane < e1s) ? __expf(pr[0]) : 0.f;
    // den via HALF-wave reduction (off<32 never crosses the head boundary):
    // within a 32-lane half each edge's wgt lives in exactly 2 lanes.
    float ws = wgt;
    #pragma unroll
    for (int off = 1; off < 32; off <<= 1) ws += __shfl_xor(ws, off);
    den = fmaf(ws, 0.5f, den);
    #pragma unroll
    for (int q = 0; q < CHUNK; q++) {
      float wq = __shfl(wgt, bb + 2 * q);
      S1 = fmaf(wq, xs[q], S1);
    }
  }
  float T = S1 / den;
  float2 bv = *(const float2*)&bias[c];
  float o0 = fmaxf(fmaf(wl.x, T, bl2.x + bv.x), 0.f);
  float o1 = fmaxf(fmaf(wl.y, T, bl2.y + bv.y), 0.f);
  unsigned short hh0 = f32_to_bf16(o0);
  unsigned short hl0 = f32_to_bf16(o0 - bf16_to_f32(hh0));
  unsigned short hh1 = f32_to_bf16(o1);
  unsigned short hl1 = f32_to_bf16(o1 - bf16_to_f32(hh1));
  *(ushort2*)&h_hi[(size_t)t * HCC + c] = make_ushort2(hh0, hh1);
  *(ushort2*)&h_lo[(size_t)t * HCC + c] = make_ushort2(hl0, hl1);
}

// ---------------- GATv2 layer 2: one wave per node ----------------
// CSR on the scalar pipe (s_load); row gathers use SGPR base + fixed VGPR
// offset (zero VALU address math). Half-wave den reduce.
__global__ void gat2_kernel(const float* __restrict__ xl, const float* __restrict__ xr,
    const int* __restrict__ offs, const int2* __restrict__ csr_pack,
    const float* __restrict__ We, const float* __restrict__ att,
    const float* __restrict__ bias,
    unsigned short* __restrict__ h_hi, unsigned short* __restrict__ h_lo, int N) {
  int t = (blockIdx.x * blockDim.x + threadIdx.x) >> 6;
  if (t >= N) return;
  int lane = threadIdx.x & 63;
  int c = lane * 2;
  float2 xrv = *(const float2*)&xr[(size_t)t * HCC + c];
  float2 wev = *(const float2*)&We[c];
  float2 atv = *(const float2*)&att[c];
  int e0s = __builtin_amdgcn_readfirstlane(offs[t]);
  int e1s = __builtin_amdgcn_readfirstlane(offs[t + 1]);
  int qlane = (lane >> 1) & 15;
  int bb = lane & 32;

  float den = 0.f, a0 = 0.f, a1 = 0.f;
  for (int base = e0s; base < e1s; base += CHUNK) {
    float2 xj[CHUNK]; float eav[CHUNK];
    #pragma unroll
    for (int q = 0; q < CHUNK; q++) {
      int ec = base + q;                   // SGPR arithmetic
      ec = ec < e1s ? ec : e1s - 1;        // s_cselect clamp
      int2 pk = csr_pack[ec];              // s_load_dwordx2
      int s = __builtin_amdgcn_readfirstlane(pk.x);
      eav[q] = __uint_as_float(__builtin_amdgcn_readfirstlane(pk.y));
      xj[q] = *(const float2*)&xl[(size_t)s * HCC + c];  // SGPR base + lane offset
    }
    float pr[CHUNK];
    #pragma unroll
    for (int q = 0; q < CHUNK; q++) {
      float m0 = fmaf(eav[q], wev.x, xrv.x + xj[q].x);
      float m1 = fmaf(eav[q], wev.y, xrv.y + xj[q].y);
      float l0 = fmaxf(m0, NEG_SLOPE * m0);
      float l1 = fmaxf(m1, NEG_SLOPE * m1);
      pr[q] = fmaf(l0, atv.x, l1 * atv.y);
    }
    FOLD_STEP(16, 8) FOLD_STEP(8, 4) FOLD_STEP(4, 2) FOLD_STEP(2, 1)
    pr[0] += __shfl_xor(pr[0], 1);
    float wgt = (base + qlane < e1s) ? __expf(pr[0]) : 0.f;
    // HALF-wave reduction: head-local denominator (2 lanes per edge per half)
    float ws = wgt;
    #pragma unroll
    for (int off = 1; off < 32; off <<= 1) ws += __shfl_xor(ws, off);
    den = fmaf(ws, 0.5f, den);
    #pragma unroll
    for (int q = 0; q < CHUNK; q++) {
      float wq = __shfl(wgt, bb + 2 * q);
      a0 = fmaf(wq, xj[q].x, a0);
      a1 = fmaf(wq, xj[q].y, a1);
    }
  }
  float inv = 1.0f / den;
  float2 bv = *(const float2*)&bias[c];
  float o0 = fmaxf(fmaf(a0, inv, bv.x), 0.f);
  float o1 = fmaxf(fmaf(a1, inv, bv.y), 0.f);
  unsigned short hh0 = f32_to_bf16(o0);
  unsigned short hl0 = f32_to_bf16(o0 - bf16_to_f32(hh0));
  unsigned short hh1 = f32_to_bf16(o1);
  unsigned short hl1 = f32_to_bf16(o1 - bf16_to_f32(hh1));
  *(ushort2*)&h_hi[(size_t)t * HCC + c] = make_ushort2(hh0, hh1);
  *(ushort2*)&h_lo[(size_t)t * HCC + c] = make_ushort2(hl0, hl1);
}

// ---------------- fused prep: W^T split (blocks 0..255) + msg_emb split (256..511) ----------------
__global__ void prep_kernel(const float* __restrict__ Wl, const float* __restrict__ Wr,
                            const float* __restrict__ msg, const float* __restrict__ fcW,
                            const float* __restrict__ fcb,
                            unsigned short* __restrict__ wt_hi, unsigned short* __restrict__ wt_lo,
                            unsigned short* __restrict__ mb_hi, unsigned short* __restrict__ mb_lo) {
  if (blockIdx.x < 256) {
    int c = blockIdx.x;        // output col 0..255
    int k = threadIdx.x;       // 0..127
    const float* W = (c < HCC) ? Wl : Wr;
    int cc = c & (HCC - 1);
    float v = W[(size_t)k * HCC + cc];
    unsigned short hi = f32_to_bf16(v);
    unsigned short lo = f32_to_bf16(v - bf16_to_f32(hi));
    wt_hi[(size_t)c * HCC + k] = hi;
    wt_lo[(size_t)c * HCC + k] = lo;
  } else {
    int r = blockIdx.x - 256, c = threadIdx.x;
    const float* mrow = &msg[(size_t)r * HCC];
    float acc = fcb[c];
    #pragma unroll 8
    for (int k = 0; k < HCC; k++) acc = fmaf(mrow[k], fcW[(size_t)k * HCC + c], acc);
    unsigned short hi = f32_to_bf16(acc);
    unsigned short lo = f32_to_bf16(acc - bf16_to_f32(hi));
    mb_hi[(size_t)r * HCC + c] = hi;
    mb_lo[(size_t)r * HCC + c] = lo;
  }
}

// ---------------- l2 transforms via bf16x3-split MFMA ----------------
__global__ __launch_bounds__(256) void l2_mfma_kernel(
    const unsigned short* __restrict__ h_hi, const unsigned short* __restrict__ h_lo,
    const unsigned short* __restrict__ wt_hi, const unsigned short* __restrict__ wt_lo,
    const float* __restrict__ bl, const float* __restrict__ br,
    float* __restrict__ xl, float* __restrict__ xr, int N) {
  __shared__ __align__(16) unsigned short bs[2][256][40];  // 40 KB
  int tid = threadIdx.x;
  int w = tid >> 6, lane = tid & 63;
  int g = lane >> 4, c15 = lane & 15;
  int nodeA = blockIdx.x * 64 + w * 16 + c15;
  int rA = nodeA < N ? nodeA : N - 1;

  bf16x8 ah[4], al[4];
  #pragma unroll
  for (int ks = 0; ks < 4; ks++) {
    int kb = ks * 32 + g * 8;
    ah[ks] = *reinterpret_cast<const bf16x8*>(&h_hi[(size_t)rA * HCC + kb]);
    al[ks] = *reinterpret_cast<const bf16x8*>(&h_lo[(size_t)rA * HCC + kb]);
  }

  f32x4 acc[16];
  #pragma unroll
  for (int f = 0; f < 16; f++) acc[f] = (f32x4){0.f, 0.f, 0.f, 0.f};

  #pragma unroll
  for (int ks = 0; ks < 4; ks++) {
    __syncthreads();
    #pragma unroll
    for (int j = 0; j < 8; j++) {
      int cidx = tid + 256 * j;            // 0..2047 granules of 16 B
      int a = cidx >> 10;
      int m = (cidx & 1023) >> 2;
      int gq = cidx & 3;
      const unsigned short* src = a ? wt_lo : wt_hi;
      bf16x8 v = *reinterpret_cast<const bf16x8*>(&src[(size_t)m * HCC + ks * 32 + gq * 8]);
      *reinterpret_cast<bf16x8*>(&bs[a][m][gq * 8]) = v;
    }
    __syncthreads();
    #pragma unroll
    for (int f = 0; f < 16; f++) {
      int rB = f * 16 + c15;
      bf16x8 bh = *reinterpret_cast<const bf16x8*>(&bs[0][rB][g * 8]);
      bf16x8 bv = *reinterpret_cast<const bf16x8*>(&bs[1][rB][g * 8]);
      acc[f] = __builtin_amdgcn_mfma_f32_16x16x32_bf16(ah[ks], bh, acc[f], 0, 0, 0);
      acc[f] = __builtin_amdgcn_mfma_f32_16x16x32_bf16(ah[ks], bv, acc[f], 0, 0, 0);
      acc[f] = __builtin_amdgcn_mfma_f32_16x16x32_bf16(al[ks], bh, acc[f], 0, 0, 0);
    }
  }

  float bcol[16];
  #pragma unroll
  for (int f = 0; f < 16; f++) {
    int col = f * 16 + c15;
    bcol[f] = (col < HCC) ? bl[col] : br[col - HCC];
  }

  #pragma unroll
  for (int r = 0; r < 4; r++) {
    int node = blockIdx.x * 64 + w * 16 + g * 4 + r;
    if (node < N) {
      #pragma unroll
      for (int f = 0; f < 16; f++) {
        int col = f * 16 + c15;
        float v = acc[f][r] + bcol[f];
        if (col < HCC) xl[(size_t)node * HCC + col] = v;
        else           xr[(size_t)node * HCC + col - HCC] = v;
      }
    }
  }
}

// ---------------- logits = h @ memb^T via bf16x3-split MFMA; row softmax ----------------
__global__ __launch_bounds__(256) void logits_mfma_kernel(
    const unsigned short* __restrict__ h_hi, const unsigned short* __restrict__ h_lo,
    const unsigned short* __restrict__ mb_hi, const unsigned short* __restrict__ mb_lo,
    float* __restrict__ out, int N) {
  __shared__ __align__(16) unsigned short bs[2][256][40];  // 40 KB
  int tid = threadIdx.x;
  int w = tid >> 6, lane = tid & 63;
  int g = lane >> 4, c15 = lane & 15;
  int nodeA = blockIdx.x * 64 + w * 16 + c15;
  int rA = nodeA < N ? nodeA : N - 1;

  bf16x8 ah[4], al[4];
  #pragma unroll
  for (int ks = 0; ks < 4; ks++) {
    int kb = ks * 32 + g * 8;
    ah[ks] = *reinterpret_cast<const bf16x8*>(&h_hi[(size_t)rA * HCC + kb]);
    al[ks] = *reinterpret_cast<const bf16x8*>(&h_lo[(size_t)rA * HCC + kb]);
  }

  f32x4 acc[16];
  #pragma unroll
  for (int f = 0; f < 16; f++) acc[f] = (f32x4){0.f, 0.f, 0.f, 0.f};

  #pragma unroll
  for (int ks = 0; ks < 4; ks++) {
    __syncthreads();
    #pragma unroll
    for (int j = 0; j < 8; j++) {
      int cidx = tid + 256 * j;
      int a = cidx >> 10;
      int m = (cidx & 1023) >> 2;
      int gq = cidx & 3;
      const unsigned short* src = a ? mb_lo : mb_hi;
      bf16x8 v = *reinterpret_cast<const bf16x8*>(&src[(size_t)m * HCC + ks * 32 + gq * 8]);
      *reinterpret_cast<bf16x8*>(&bs[a][m][gq * 8]) = v;
    }
    __syncthreads();
    #pragma unroll
    for (int f = 0; f < 16; f++) {
      int rB = f * 16 + c15;
      bf16x8 bh = *reinterpret_cast<const bf16x8*>(&bs[0][rB][g * 8]);
      bf16x8 bl = *reinterpret_cast<const bf16x8*>(&bs[1][rB][g * 8]);
      acc[f] = __builtin_amdgcn_mfma_f32_16x16x32_bf16(ah[ks], bh, acc[f], 0, 0, 0);
      acc[f] = __builtin_amdgcn_mfma_f32_16x16x32_bf16(ah[ks], bl, acc[f], 0, 0, 0);
      acc[f] = __builtin_amdgcn_mfma_f32_16x16x32_bf16(al[ks], bh, acc[f], 0, 0, 0);
    }
  }

  #pragma unroll
  for (int r = 0; r < 4; r++) {
    int node = blockIdx.x * 64 + w * 16 + g * 4 + r;
    float mx = acc[0][r];
    #pragma unroll
    for (int f = 1; f < 16; f++) mx = fmaxf(mx, acc[f][r]);
    #pragma unroll
    for (int off = 1; off < 16; off <<= 1) mx = fmaxf(mx, __shfl_xor(mx, off));
    float e[16], s = 0.f;
    #pragma unroll
    for (int f = 0; f < 16; f++) { e[f] = expf(acc[f][r] - mx); s += e[f]; }
    #pragma unroll
    for (int off = 1; off < 16; off <<= 1) s += __shfl_xor(s, off);
    float inv = 1.0f / s;
    if (node < N) {
      #pragma unroll
      for (int f = 0; f < 16; f++) out[(size_t)node * 256 + f * 16 + c15] = e[f] * inv;
    }
  }
}

extern "C" void kernel_launch(void* const* d_in, const int* in_sizes, int n_in,
                              void* d_out, int out_size, void* d_ws, size_t ws_size,
                              hipStream_t stream) {
  (void)n_in; (void)out_size; (void)ws_size;
  const float* message  = (const float*)d_in[0];
  const float* x        = (const float*)d_in[1];
  const float* edge_attr= (const float*)d_in[2];
  const float* c1_Wl   = (const float*)d_in[3];
  const float* c1_bl   = (const float*)d_in[4];
  const float* c1_Wr   = (const float*)d_in[5];
  const float* c1_br   = (const float*)d_in[6];
  const float* c1_We   = (const float*)d_in[7];
  const float* c1_att  = (const float*)d_in[8];
  const float* c1_bias = (const float*)d_in[9];
  const float* c2_Wl   = (const float*)d_in[10];
  const float* c2_bl   = (const float*)d_in[11];
  const float* c2_Wr   = (const float*)d_in[12];
  const float* c2_br   = (const float*)d_in[13];
  const float* c2_We   = (const float*)d_in[14];
  const float* c2_att  = (const float*)d_in[15];
  const float* c2_bias = (const float*)d_in[16];
  const float* fc1_W   = (const float*)d_in[17];
  const float* fc1_b   = (const float*)d_in[18];
  const int* edge_index = (const int*)d_in[19];

  const int N = in_sizes[1];          // 50000
  const int E = in_sizes[2];          // 500000
  const int Et = E + N;
  float* out = (float*)d_out;

  char* wsb = (char*)d_ws;
  size_t woff = 0;
  auto alloc = [&](size_t bytes) -> void* {
    void* p = wsb + woff;
    woff += (bytes + 255) & ~(size_t)255;
    return p;
  };
  float* xl     = (float*)alloc((size_t)N * HCC * 4);
  float* xr     = (float*)alloc((size_t)N * HCC * 4);
  float* hb     = (float*)alloc((size_t)N * HCC * 4);  // holds h splits (h1, then h2)
  unsigned short* mb_hi = (unsigned short*)alloc((size_t)256 * HCC * 2);
  unsigned short* mb_lo = (unsigned short*)alloc((size_t)256 * HCC * 2);
  unsigned short* wt_hi = (unsigned short*)alloc((size_t)256 * HCC * 2);
  unsigned short* wt_lo = (unsigned short*)alloc((size_t)256 * HCC * 2);
  float* ea_sum = (float*)alloc(256);
  int* deg      = (int*)alloc((size_t)N * 4);
  int* offs     = (int*)alloc((size_t)(N + 1) * 4);
  int* bsum     = (int*)alloc(256 * 4);
  int* cursor   = (int*)alloc((size_t)N * 4);
  int2* csr_pack= (int2*)alloc((size_t)Et * 8);

  unsigned short* h_hi = (unsigned short*)hb;
  unsigned short* h_lo = h_hi + (size_t)N * HCC;

  const int NB = (N + 1023) / 1024;   // 49 blocks (<=64 required)

  init_kernel<<<(N + 256) / 256, 256, 0, stream>>>(deg, cursor, ea_sum, N);
  ea_reduce_kernel<<<256, 256, 0, stream>>>(edge_attr, ea_sum, E);
  deg_count_kernel<<<(Et + 255) / 256, 256, 0, stream>>>(edge_index, deg, E, N);
  blocksum_kernel<<<NB, 1024, 0, stream>>>(deg, bsum, N);
  scanfinal_kernel<<<NB, 1024, 0, stream>>>(deg, bsum, offs, N, NB);
  scatter_kernel<<<(Et + 255) / 256, 256, 0, stream>>>(edge_index, edge_attr, ea_sum,
                                                       offs, cursor, csr_pack, E, N);
  prep_kernel<<<512, 128, 0, stream>>>(c2_Wl, c2_Wr, message, fc1_W, fc1_b,
                                       wt_hi, wt_lo, mb_hi, mb_lo);
  gat1_kernel<<<(N + 3) / 4, 256, 0, stream>>>(x, offs, csr_pack,
                                               c1_Wl, c1_bl, c1_Wr, c1_br,
                                               c1_We, c1_att, c1_bias, h_hi, h_lo, N);
  l2_mfma_kernel<<<(N + 63) / 64, 256, 0, stream>>>(h_hi, h_lo, wt_hi, wt_lo,
                                                    c2_bl, c2_br, xl, xr, N);
  gat2_kernel<<<(N + 3) / 4, 256, 0, stream>>>(xl, xr, offs, csr_pack,
                                               c2_We, c2_att, c2_bias, h_hi, h_lo, N);
  logits_mfma_kernel<<<(N + 63) / 64, 256, 0, stream>>>(h_hi, h_lo, mb_hi, mb_lo, out, N);
}